// Round 1
// baseline (382.738 us; speedup 1.0000x reference)
//
#include <hip/hip_runtime.h>
#include <hip/hip_bf16.h>

#define NB 8192   // batch (rows of A, rows of B, cos is NB x NB)
#define ND 1024   // feature dim

typedef __bf16 bf16x8 __attribute__((ext_vector_type(8)));
typedef float  f32x4  __attribute__((ext_vector_type(4)));

// async global -> LDS, 16B per lane. LDS dest is wave-uniform base + lane*16.
__device__ inline void gload_lds16(const void* g, void* l) {
    __builtin_amdgcn_global_load_lds(
        (const __attribute__((address_space(1))) unsigned int*)g,
        (__attribute__((address_space(3))) unsigned int*)l,
        16, 0, 0);
}

__device__ inline unsigned short f2bf(float x) {
    // round-to-nearest-even f32 -> bf16 (inputs are finite gaussians; no NaN path)
    unsigned int u = __float_as_uint(x);
    return (unsigned short)((u + 0x7fffu + ((u >> 16) & 1u)) >> 16);
}

// ---------------------------------------------------------------------------
// Kernel 1: per-row L2 norms of A and B + bf16 conversion into workspace.
// One wave per row; 4096 blocks x 256 threads (blocks <2048 -> A, else B).
// ---------------------------------------------------------------------------
__global__ __launch_bounds__(256) void prep_kernel(
    const float* __restrict__ A, const float* __restrict__ Bm,
    unsigned short* __restrict__ wa, unsigned short* __restrict__ wb,
    float* __restrict__ na, float* __restrict__ nb)
{
    int b = blockIdx.x;
    int wid = threadIdx.x >> 6, lane = threadIdx.x & 63;
    const float* src; unsigned short* dst; float* nrm; int row;
    if (b < 2048) { src = A;  dst = wa; nrm = na; row = b * 4 + wid; }
    else          { src = Bm; dst = wb; nrm = nb; row = (b - 2048) * 4 + wid; }

    const float*    rp = src + (size_t)row * ND;
    unsigned short* wp = dst + (size_t)row * ND;

    float ss = 0.f;
#pragma unroll
    for (int t = 0; t < 4; ++t) {
        int c = lane * 4 + t * 256;
        float4 v = *reinterpret_cast<const float4*>(rp + c);
        ss += v.x * v.x + v.y * v.y + v.z * v.z + v.w * v.w;
        ushort4 u;
        u.x = f2bf(v.x); u.y = f2bf(v.y); u.z = f2bf(v.z); u.w = f2bf(v.w);
        *reinterpret_cast<ushort4*>(wp + c) = u;
    }
#pragma unroll
    for (int off = 32; off; off >>= 1) ss += __shfl_xor(ss, off);
    if (lane == 0) nrm[row] = sqrtf(ss);
}

// ---------------------------------------------------------------------------
// Kernel 2: C[r][c] = dot(a_r, b_c) / max(na[r]*nb[c], eps)
// 128x128 tile, BK=32, 4 waves (2x2), each wave 64x64 via 4x4 of 16x16x32 MFMA.
// Double-buffered LDS staged with global_load_lds (16B). m97 structure.
// ---------------------------------------------------------------------------
__global__ __launch_bounds__(256) void gemm_cos(
    const unsigned short* __restrict__ wa, const unsigned short* __restrict__ wb,
    const float* __restrict__ na, const float* __restrict__ nb,
    float* __restrict__ C)
{
    __shared__ unsigned short lds[2][2][128 * 32];   // 2 bufs x (A,B) x 8KB

    // XCD-aware swizzle: 4096 blocks, 8 XCDs, 512 contiguous tiles per XCD.
    int bid = blockIdx.x;
    int swz = (bid & 7) * 512 + (bid >> 3);
    int tm = swz >> 6, tn = swz & 63;

    const int tid  = threadIdx.x;
    const int lane = tid & 63;
    const int wid  = tid >> 6;
    const int wr   = wid >> 1, wc = wid & 1;

    const size_t m0 = (size_t)tm * 128, n0 = (size_t)tn * 128;

    // staging: thread t covers tile bytes t*16 (+issue*4096): row=t/4, col=(t&3)*8
    const unsigned short* ga = wa + (m0 + (tid >> 2)) * ND + (tid & 3) * 8;
    const unsigned short* gb = wb + (n0 + (tid >> 2)) * ND + (tid & 3) * 8;

    f32x4 acc[4][4];
#pragma unroll
    for (int i = 0; i < 4; ++i)
#pragma unroll
        for (int j = 0; j < 4; ++j) acc[i][j] = (f32x4){0.f, 0.f, 0.f, 0.f};

    const int arow = wr * 64 + (lane & 15);
    const int brow = wc * 64 + (lane & 15);
    const int koff = (lane >> 4) * 8;

    auto stage = [&](int buf, int kt) {
        unsigned short* lA = &lds[buf][0][wid * 512];
        unsigned short* lB = &lds[buf][1][wid * 512];
        const unsigned short* gA = ga + kt * 32;
        const unsigned short* gB = gb + kt * 32;
        gload_lds16(gA,            lA);
        gload_lds16(gA + 64 * ND,  lA + 2048);
        gload_lds16(gB,            lB);
        gload_lds16(gB + 64 * ND,  lB + 2048);
    };
    auto compute = [&](int buf) {
        const unsigned short* lA = lds[buf][0];
        const unsigned short* lB = lds[buf][1];
        bf16x8 af[4], bfr[4];
#pragma unroll
        for (int m = 0; m < 4; ++m)
            af[m] = *reinterpret_cast<const bf16x8*>(&lA[(arow + m * 16) * 32 + koff]);
#pragma unroll
        for (int n = 0; n < 4; ++n)
            bfr[n] = *reinterpret_cast<const bf16x8*>(&lB[(brow + n * 16) * 32 + koff]);
#pragma unroll
        for (int m = 0; m < 4; ++m)
#pragma unroll
            for (int n = 0; n < 4; ++n)
                acc[m][n] = __builtin_amdgcn_mfma_f32_16x16x32_bf16(
                    af[m], bfr[n], acc[m][n], 0, 0, 0);
    };

    stage(0, 0);
    __syncthreads();                       // drains vmcnt(0)
    int cur = 0;
    for (int kt = 0; kt < (ND / 32) - 1; ++kt) {
        stage(cur ^ 1, kt + 1);
        compute(cur);
        __syncthreads();
        cur ^= 1;
    }
    compute(cur);

    // epilogue: scale by 1/max(na*nb, eps). C/D layout: col=lane&15, row=(lane>>4)*4+j
#pragma unroll
    for (int mi = 0; mi < 4; ++mi) {
        int rb = (int)m0 + wr * 64 + mi * 16 + (lane >> 4) * 4;
#pragma unroll
        for (int ni = 0; ni < 4; ++ni) {
            int c = (int)n0 + wc * 64 + ni * 16 + (lane & 15);
            float nbv = nb[c];
#pragma unroll
            for (int j = 0; j < 4; ++j) {
                int r = rb + j;
                float d = fmaxf(na[r] * nbv, 1e-8f);
                C[(size_t)r * NB + c] = acc[mi][ni][j] / d;
            }
        }
    }
}

// ---------------------------------------------------------------------------
// Kernel 3: per-row loss. cos in [-1,1] -> no max subtraction needed.
// per_row = log(sum_j exp(cos_ij)) - (sum_{label_j==label_i} cos_ij)/cnt_i
// One wave per row, labels staged in LDS. Scalar loads (cos base is 4B-aligned).
// ---------------------------------------------------------------------------
__global__ __launch_bounds__(256) void loss_rows(
    const float* __restrict__ cosm, const int* __restrict__ labels,
    float* __restrict__ per_row)
{
    __shared__ int ll[NB];
    int tid = threadIdx.x;
#pragma unroll
    for (int t = 0; t < 8; ++t) {
        int idx = (tid + t * 256) * 4;
        *reinterpret_cast<int4*>(&ll[idx]) =
            *reinterpret_cast<const int4*>(&labels[idx]);
    }
    __syncthreads();

    int wid = tid >> 6, lane = tid & 63;
    int row = blockIdx.x * 4 + wid;
    int lab = ll[row];
    const float* rp = cosm + (size_t)row * NB;

    float s = 0.f, ms = 0.f, cnt = 0.f;
    for (int t = 0; t < NB / 64; ++t) {
        int c = lane + t * 64;
        float v = rp[c];
        s += __expf(v);
        if (ll[c] == lab) { ms += v; cnt += 1.f; }
    }
#pragma unroll
    for (int off = 32; off; off >>= 1) {
        s   += __shfl_xor(s, off);
        ms  += __shfl_xor(ms, off);
        cnt += __shfl_xor(cnt, off);
    }
    if (lane == 0) per_row[row] = logf(s) - ms / cnt;
}

// ---------------------------------------------------------------------------
// Kernel 4: deterministic mean of per_row -> out[0]
// ---------------------------------------------------------------------------
__global__ __launch_bounds__(256) void finalize(
    const float* __restrict__ per_row, float* __restrict__ out)
{
    __shared__ float sm[256];
    float s = 0.f;
    for (int i = threadIdx.x; i < NB; i += 256) s += per_row[i];
    sm[threadIdx.x] = s;
    __syncthreads();
    for (int k = 128; k; k >>= 1) {
        if (threadIdx.x < k) sm[threadIdx.x] += sm[threadIdx.x + k];
        __syncthreads();
    }
    if (threadIdx.x == 0) out[0] = sm[0] * (1.0f / (float)NB);
}

extern "C" void kernel_launch(void* const* d_in, const int* in_sizes, int n_in,
                              void* d_out, int out_size, void* d_ws, size_t ws_size,
                              hipStream_t stream) {
    const int*   labels = (const int*)d_in[0];
    const float* A      = (const float*)d_in[1];
    const float* Bm     = (const float*)d_in[2];
    float* out = (float*)d_out;

    // workspace layout (needs ~33.6 MB)
    char* ws = (char*)d_ws;
    unsigned short* wa = (unsigned short*)(ws);                     // 16 MB
    unsigned short* wb = (unsigned short*)(ws + 16777216);          // 16 MB
    float* na      = (float*)(ws + 33554432);                       // 32 KB
    float* nb      = (float*)(ws + 33554432 + 32768);               // 32 KB
    float* per_row = (float*)(ws + 33554432 + 65536);               // 32 KB

    float* cosm = out + 1;   // out[0]=loss, out[1..] = cos_score row-major

    prep_kernel<<<4096, 256, 0, stream>>>(A, Bm, wa, wb, na, nb);
    gemm_cos  <<<4096, 256, 0, stream>>>(wa, wb, na, nb, cosm);
    loss_rows <<<2048, 256, 0, stream>>>(cosm, labels, per_row);
    finalize  <<<1,    256, 0, stream>>>(per_row, out);
}

// Round 2
// 261.526 us; speedup vs baseline: 1.4635x; 1.4635x over previous
//
#include <hip/hip_runtime.h>
#include <hip/hip_bf16.h>

#define NB 8192   // batch
#define ND 1024   // feature dim

typedef __bf16 bf16x8 __attribute__((ext_vector_type(8)));
typedef float  f32x4  __attribute__((ext_vector_type(4)));

// async global -> LDS, 16B per lane. LDS dest = wave-uniform base + lane*16.
__device__ inline void gload_lds16(const void* g, void* l) {
    __builtin_amdgcn_global_load_lds(
        (const __attribute__((address_space(1))) unsigned int*)g,
        (__attribute__((address_space(3))) unsigned int*)l,
        16, 0, 0);
}

__device__ inline unsigned short f2bf(float x) {
    unsigned int u = __float_as_uint(x);
    return (unsigned short)((u + 0x7fffu + ((u >> 16) & 1u)) >> 16);
}

#define BARRIER() asm volatile("s_barrier" ::: "memory")
#define VMCNT(n)  asm volatile("s_waitcnt vmcnt(" #n ")" ::: "memory")
#define LGKM0()   do { asm volatile("s_waitcnt lgkmcnt(0)" ::: "memory"); \
                       __builtin_amdgcn_sched_barrier(0); } while (0)

// ---------------------------------------------------------------------------
// Kernel 1: per-row L2 norms of A and B + bf16 conversion into workspace.
// ---------------------------------------------------------------------------
__global__ __launch_bounds__(256) void prep_kernel(
    const float* __restrict__ A, const float* __restrict__ Bm,
    unsigned short* __restrict__ wa, unsigned short* __restrict__ wb,
    float* __restrict__ na, float* __restrict__ nb)
{
    int b = blockIdx.x;
    int wid = threadIdx.x >> 6, lane = threadIdx.x & 63;
    const float* src; unsigned short* dst; float* nrm; int row;
    if (b < 2048) { src = A;  dst = wa; nrm = na; row = b * 4 + wid; }
    else          { src = Bm; dst = wb; nrm = nb; row = (b - 2048) * 4 + wid; }

    const float*    rp = src + (size_t)row * ND;
    unsigned short* wp = dst + (size_t)row * ND;

    float ss = 0.f;
#pragma unroll
    for (int t = 0; t < 4; ++t) {
        int c = lane * 4 + t * 256;
        float4 v = *reinterpret_cast<const float4*>(rp + c);
        ss += v.x * v.x + v.y * v.y + v.z * v.z + v.w * v.w;
        ushort4 u;
        u.x = f2bf(v.x); u.y = f2bf(v.y); u.z = f2bf(v.z); u.w = f2bf(v.w);
        *reinterpret_cast<ushort4*>(wp + c) = u;
    }
#pragma unroll
    for (int off = 32; off; off >>= 1) ss += __shfl_xor(ss, off);
    if (lane == 0) nrm[row] = sqrtf(ss);
}

// ---------------------------------------------------------------------------
// Kernel 2: label histogram (integer LDS atomics -> deterministic).
// ---------------------------------------------------------------------------
__global__ __launch_bounds__(256) void hist_kernel(
    const int* __restrict__ labels, int* __restrict__ hist)
{
    __shared__ int h[128];
    int tid = threadIdx.x;
    if (tid < 128) h[tid] = 0;
    __syncthreads();
    for (int i = tid; i < NB; i += 256) atomicAdd(&h[labels[i]], 1);
    __syncthreads();
    if (tid < 128) hist[tid] = h[tid];
}

// ---------------------------------------------------------------------------
// Kernel 3: 256x256-tile bf16 MFMA GEMM, BK=32, 4 LDS buffers (128 KiB),
// stage-2-tiles-ahead with counted vmcnt (never 0 in main loop), raw
// s_barrier, setprio around MFMA clusters, T2 XOR-swizzled LDS.
// Epilogue: scale to cos, write C, and reduce per-row loss partials.
// ---------------------------------------------------------------------------
__global__ __launch_bounds__(512, 2) void gemm_cos(
    const unsigned short* __restrict__ wa, const unsigned short* __restrict__ wb,
    const float* __restrict__ na, const float* __restrict__ nb,
    const int* __restrict__ labels,
    float* __restrict__ C, float* __restrict__ pe, float* __restrict__ pm)
{
    // [buf 4][A/B 2][half 2][128 rows x 32 cols] bf16 = 128 KiB
    __shared__ unsigned short lds[4 * 16384];

    // XCD-aware, column-major within XCD: each XCD owns 4 tile-rows (A 2MB,
    // L2-resident); tn advances so B panels stream while A stays hot.
    const int bid = blockIdx.x;                 // 1024 blocks
    const int tm  = (bid & 7) * 4 + ((bid >> 3) & 3);
    const int tn  = bid >> 5;

    const int tid  = threadIdx.x;
    const int lane = tid & 63;
    const int wid  = tid >> 6;
    const int wr   = wid >> 2, wc = wid & 3;
    const int l15  = lane & 15, lg = lane >> 4;

    const int m0 = tm * 256, n0 = tn * 256;

    // Staging: linear LDS dest (slot = tid*16B -> row tid>>2, granule tid&3),
    // inverse-swizzled global source granule (g ^ (row>>1)&3).
    const int srow = tid >> 2;
    const int sg   = (tid & 3) ^ ((tid >> 3) & 3);
    const unsigned short* gA = wa + (size_t)(m0 + srow) * ND + sg * 8;
    const unsigned short* gB = wb + (size_t)(n0 + srow) * ND + sg * 8;
    const int stA = wid * 512;   // wave-uniform LDS base (shorts) within a half

    // Swizzled read granule (shorts): g' = (lane>>4) ^ ((row>>1)&3); row bits
    // from l15 only (m*16, q*64, n*16, 64 are all 0 mod 8).
    const int kg  = ((lg ^ ((lane >> 1) & 3)) * 8);
    const int rdA = wr * 4096 + l15 * 32 + kg;                         // + q*2048 + m*512
    const int rdB = 8192 + (wc >> 1) * 4096 + ((wc & 1) * 64 + l15) * 32 + kg;  // + n*512

    f32x4 acc[8][4];
#pragma unroll
    for (int i = 0; i < 8; ++i)
#pragma unroll
        for (int j = 0; j < 4; ++j) acc[i][j] = (f32x4){0.f, 0.f, 0.f, 0.f};

#define STAGE(t, X, h) gload_lds16( \
        (X ? gB : gA) + (size_t)(h) * 128 * ND + (t) * 32, \
        &lds[(((t) & 3) * 16384) + (X) * 8192 + (h) * 4096 + stA])

#define PHASE(t, q, SA, SB, ...) { \
    const int bufo = ((t) & 3) * 16384; \
    bf16x8 af[4], bq[4]; \
    _Pragma("unroll") \
    for (int m_ = 0; m_ < 4; ++m_) \
        af[m_] = *reinterpret_cast<const bf16x8*>(&lds[bufo + rdA + (q) * 2048 + m_ * 512]); \
    _Pragma("unroll") \
    for (int n_ = 0; n_ < 4; ++n_) \
        bq[n_] = *reinterpret_cast<const bf16x8*>(&lds[bufo + rdB + n_ * 512]); \
    if (SA) { STAGE((t) + 2, 0, 0); STAGE((t) + 2, 0, 1); } \
    if (SB) { STAGE((t) + 2, 1, 0); STAGE((t) + 2, 1, 1); } \
    BARRIER(); \
    LGKM0(); \
    __builtin_amdgcn_s_setprio(1); \
    _Pragma("unroll") \
    for (int m_ = 0; m_ < 4; ++m_) \
        _Pragma("unroll") \
        for (int n_ = 0; n_ < 4; ++n_) \
            acc[(q) * 4 + m_][n_] = __builtin_amdgcn_mfma_f32_16x16x32_bf16( \
                af[m_], bq[n_], acc[(q) * 4 + m_][n_], 0, 0, 0); \
    __builtin_amdgcn_s_setprio(0); \
    __VA_ARGS__; \
    BARRIER(); }

    // Prologue: tiles 0 and 1 fully staged (8 loads in flight/wave).
    STAGE(0, 0, 0); STAGE(0, 0, 1); STAGE(0, 1, 0); STAGE(0, 1, 1);
    STAGE(1, 0, 0); STAGE(1, 0, 1); STAGE(1, 1, 0); STAGE(1, 1, 1);
    VMCNT(4);            // tile 0 complete; tile 1 still in flight
    BARRIER();

    for (int t = 0; t < 30; ++t) {
        PHASE(t, 0, 1, 0, (void)0);          // stage A-halves of tile t+2
        PHASE(t, 1, 0, 1, VMCNT(4));         // stage B-halves; wait tile t+1
    }
    PHASE(30, 0, 0, 0, (void)0);
    PHASE(30, 1, 0, 0, VMCNT(0));            // drain: tile 31 ready
    PHASE(31, 0, 0, 0, (void)0);
    PHASE(31, 1, 0, 0, (void)0);

#undef PHASE
#undef STAGE

    // ---------------- epilogue: cos write + fused loss partials ------------
    __syncthreads();                 // full drain; LDS buffers now reusable
    float* pl = reinterpret_cast<float*>(lds);   // [256 rows][4 wc][2] floats

    float nbv[4]; int labc[4];
#pragma unroll
    for (int n = 0; n < 4; ++n) {
        int c = n0 + wc * 64 + n * 16 + l15;
        nbv[n] = nb[c]; labc[n] = labels[c];
    }

#pragma unroll
    for (int m = 0; m < 8; ++m) {
#pragma unroll
        for (int jj = 0; jj < 4; ++jj) {
            int rl = wr * 128 + m * 16 + lg * 4 + jj;   // 0..255
            int r  = m0 + rl;
            float nav = na[r]; int labr = labels[r];
            float es = 0.f, ms = 0.f;
#pragma unroll
            for (int n = 0; n < 4; ++n) {
                int c = n0 + wc * 64 + n * 16 + l15;
                float v = acc[m][n][jj] / fmaxf(nav * nbv[n], 1e-8f);
                C[(size_t)r * NB + c] = v;
                es += __expf(v);
                ms += (labc[n] == labr) ? v : 0.f;
            }
#pragma unroll
            for (int off = 1; off < 16; off <<= 1) {
                es += __shfl_xor(es, off);
                ms += __shfl_xor(ms, off);
            }
            if (l15 == 0) {
                int o = (rl * 4 + wc) * 2;
                pl[o] = es; pl[o + 1] = ms;
            }
        }
    }
    __syncthreads();
    if (tid < 256) {
        float es = 0.f, ms = 0.f;
#pragma unroll
        for (int w = 0; w < 4; ++w) {
            es += pl[(tid * 4 + w) * 2];
            ms += pl[(tid * 4 + w) * 2 + 1];
        }
        int grow = m0 + tid;
        pe[tn * NB + grow] = es;
        pm[tn * NB + grow] = ms;
    }
}

// ---------------------------------------------------------------------------
// Kernel 4: reduce column-tile partials -> per-row loss.
// ---------------------------------------------------------------------------
__global__ __launch_bounds__(256) void loss_final(
    const float* __restrict__ pe, const float* __restrict__ pm,
    const int* __restrict__ labels, const int* __restrict__ hist,
    float* __restrict__ per_row)
{
    int row = blockIdx.x * 256 + threadIdx.x;
    float es = 0.f, ms = 0.f;
#pragma unroll
    for (int t = 0; t < 32; ++t) {
        es += pe[t * NB + row];
        ms += pm[t * NB + row];
    }
    per_row[row] = logf(es) - ms / (float)hist[labels[row]];
}

// ---------------------------------------------------------------------------
// Kernel 5: deterministic mean of per_row -> out[0]
// ---------------------------------------------------------------------------
__global__ __launch_bounds__(256) void finalize(
    const float* __restrict__ per_row, float* __restrict__ out)
{
    __shared__ float sm[256];
    float s = 0.f;
    for (int i = threadIdx.x; i < NB; i += 256) s += per_row[i];
    sm[threadIdx.x] = s;
    __syncthreads();
    for (int k = 128; k; k >>= 1) {
        if (threadIdx.x < k) sm[threadIdx.x] += sm[threadIdx.x + k];
        __syncthreads();
    }
    if (threadIdx.x == 0) out[0] = sm[0] * (1.0f / (float)NB);
}

extern "C" void kernel_launch(void* const* d_in, const int* in_sizes, int n_in,
                              void* d_out, int out_size, void* d_ws, size_t ws_size,
                              hipStream_t stream) {
    const int*   labels = (const int*)d_in[0];
    const float* A      = (const float*)d_in[1];
    const float* Bm     = (const float*)d_in[2];
    float* out = (float*)d_out;

    // workspace layout (~34.2 MB)
    char* ws = (char*)d_ws;
    unsigned short* wa = (unsigned short*)(ws);                     // 16 MB
    unsigned short* wb = (unsigned short*)(ws + 16777216);          // 16 MB
    float* na      = (float*)(ws + 33554432);                       // 32 KB
    float* nb      = (float*)(ws + 33554432 + 32768);               // 32 KB
    float* per_row = (float*)(ws + 33554432 + 65536);               // 32 KB
    int*   hist    = (int*)  (ws + 33554432 + 98304);               // 512 B
    float* pe      = (float*)(ws + 33554432 + 131072);              // 1 MB
    float* pm      = (float*)(ws + 33554432 + 131072 + 1048576);    // 1 MB

    float* cosm = out + 1;   // out[0]=loss, out[1..] = cos_score row-major

    prep_kernel<<<4096, 256, 0, stream>>>(A, Bm, wa, wb, na, nb);
    hist_kernel<<<1,    256, 0, stream>>>(labels, hist);
    gemm_cos   <<<1024, 512, 0, stream>>>(wa, wb, na, nb, labels, cosm, pe, pm);
    loss_final <<<32,   256, 0, stream>>>(pe, pm, labels, hist, per_row);
    finalize   <<<1,    256, 0, stream>>>(per_row, out);
}

// Round 3
// 244.456 us; speedup vs baseline: 1.5657x; 1.0698x over previous
//
#include <hip/hip_runtime.h>
#include <hip/hip_bf16.h>

#define NB 8192   // batch
#define ND 1024   // feature dim

typedef __bf16 bf16x8 __attribute__((ext_vector_type(8)));
typedef float  f32x4  __attribute__((ext_vector_type(4)));

// async global -> LDS, 16B per lane. LDS dest = wave-uniform base + lane*16.
__device__ inline void gload_lds16(const void* g, void* l) {
    __builtin_amdgcn_global_load_lds(
        (const __attribute__((address_space(1))) unsigned int*)g,
        (__attribute__((address_space(3))) unsigned int*)l,
        16, 0, 0);
}

__device__ inline unsigned short f2bf(float x) {
    unsigned int u = __float_as_uint(x);
    return (unsigned short)((u + 0x7fffu + ((u >> 16) & 1u)) >> 16);
}

#define BARRIER() asm volatile("s_barrier" ::: "memory")
#define VMCNT(n)  asm volatile("s_waitcnt vmcnt(" #n ")" ::: "memory")

// ---------------------------------------------------------------------------
// Kernel 1: per-row L2 norms of A and B + bf16 conversion into workspace.
// ---------------------------------------------------------------------------
__global__ __launch_bounds__(256) void prep_kernel(
    const float* __restrict__ A, const float* __restrict__ Bm,
    unsigned short* __restrict__ wa, unsigned short* __restrict__ wb,
    float* __restrict__ na, float* __restrict__ nb)
{
    int b = blockIdx.x;
    int wid = threadIdx.x >> 6, lane = threadIdx.x & 63;
    const float* src; unsigned short* dst; float* nrm; int row;
    if (b < 2048) { src = A;  dst = wa; nrm = na; row = b * 4 + wid; }
    else          { src = Bm; dst = wb; nrm = nb; row = (b - 2048) * 4 + wid; }

    const float*    rp = src + (size_t)row * ND;
    unsigned short* wp = dst + (size_t)row * ND;

    float ss = 0.f;
#pragma unroll
    for (int t = 0; t < 4; ++t) {
        int c = lane * 4 + t * 256;
        float4 v = *reinterpret_cast<const float4*>(rp + c);
        ss += v.x * v.x + v.y * v.y + v.z * v.z + v.w * v.w;
        ushort4 u;
        u.x = f2bf(v.x); u.y = f2bf(v.y); u.z = f2bf(v.z); u.w = f2bf(v.w);
        *reinterpret_cast<ushort4*>(wp + c) = u;
    }
#pragma unroll
    for (int off = 32; off; off >>= 1) ss += __shfl_xor(ss, off);
    if (lane == 0) nrm[row] = sqrtf(ss);
}

// ---------------------------------------------------------------------------
// Kernel 2: label histogram (integer LDS atomics -> deterministic).
// ---------------------------------------------------------------------------
__global__ __launch_bounds__(256) void hist_kernel(
    const int* __restrict__ labels, int* __restrict__ hist)
{
    __shared__ int h[128];
    int tid = threadIdx.x;
    if (tid < 128) h[tid] = 0;
    __syncthreads();
    for (int i = tid; i < NB; i += 256) atomicAdd(&h[labels[i]], 1);
    __syncthreads();
    if (tid < 128) hist[tid] = h[tid];
}

// ---------------------------------------------------------------------------
// Kernel 3: 256x256-tile bf16 MFMA GEMM, BK=32, 4 LDS buffers (128 KiB),
// stage-2-tiles-ahead. ONE barrier + ONE counted VMCNT per K-tile; no lgkm
// fences — the compiler software-pipelines ds_read returns under MFMA within
// each fully-unrolled inter-barrier region. B-frags read once per K-tile
// (12 ds_read_b128/tile/wave). T2 swizzle + XCD-column block mapping kept.
// Epilogue: scale to cos, write C, reduce per-row loss partials (fused).
// ---------------------------------------------------------------------------
__global__ __launch_bounds__(512, 2) void gemm_cos(
    const unsigned short* __restrict__ wa, const unsigned short* __restrict__ wb,
    const float* __restrict__ na, const float* __restrict__ nb,
    const int* __restrict__ labels,
    float* __restrict__ C, float* __restrict__ pe, float* __restrict__ pm)
{
    // [buf 4][A/B 2][half 2][128 rows x 32 cols] bf16 = 128 KiB
    __shared__ unsigned short lds[4 * 16384];

    const int bid = blockIdx.x;                 // 1024 blocks
    const int tm  = (bid & 7) * 4 + ((bid >> 3) & 3);
    const int tn  = bid >> 5;

    const int tid  = threadIdx.x;
    const int lane = tid & 63;
    const int wid  = tid >> 6;
    const int wr   = wid >> 2, wc = wid & 3;
    const int l15  = lane & 15, lg = lane >> 4;

    const int m0 = tm * 256, n0 = tn * 256;

    // Staging: linear LDS dest (row tid>>2, granule tid&3), inverse-swizzled
    // global source granule. 4 base pointers so unrolled offsets are imm.
    const int srow = tid >> 2;
    const int sg   = (tid & 3) ^ ((tid >> 3) & 3);
    const unsigned short* gA0 = wa + (size_t)(m0 + srow) * ND + sg * 8;
    const unsigned short* gA1 = gA0 + 128 * ND;
    const unsigned short* gB0 = wb + (size_t)(n0 + srow) * ND + sg * 8;
    const unsigned short* gB1 = gB0 + 128 * ND;
    const int stA = wid * 512;   // wave-uniform LDS base (shorts) within a half

    // Swizzled read granule: g' = (lane>>4) ^ ((row>>1)&3), row bits from l15.
    const int kg  = ((lg ^ ((lane >> 1) & 3)) * 8);
    const int rdA = wr * 4096 + l15 * 32 + kg;                              // + q*2048 + m*512
    const int rdB = 8192 + (wc >> 1) * 4096 + ((wc & 1) * 64 + l15) * 32 + kg;  // + n*512

    f32x4 acc[8][4];
#pragma unroll
    for (int i = 0; i < 8; ++i)
#pragma unroll
        for (int j = 0; j < 4; ++j) acc[i][j] = (f32x4){0.f, 0.f, 0.f, 0.f};

    bf16x8 af_a[4], af_b[4], bq_a[4], bq_b[4];

#define STAGE(t, X, h) gload_lds16( \
        (X ? (h ? gB1 : gB0) : (h ? gA1 : gA0)) + (t) * 32, \
        &lds[(((t) & 3) * 16384) + (X) * 8192 + (h) * 4096 + stA])

#define RD_A(dst, t, q) { _Pragma("unroll") \
    for (int m_ = 0; m_ < 4; ++m_) \
        dst[m_] = *reinterpret_cast<const bf16x8*>( \
            &lds[((t) & 3) * 16384 + rdA + (q) * 2048 + m_ * 512]); }

#define RD_B(dst, t) { _Pragma("unroll") \
    for (int n_ = 0; n_ < 4; ++n_) \
        dst[n_] = *reinterpret_cast<const bf16x8*>( \
            &lds[((t) & 3) * 16384 + rdB + n_ * 512]); }

#define MM(afx, bqx, q) { \
    __builtin_amdgcn_s_setprio(1); \
    _Pragma("unroll") \
    for (int m_ = 0; m_ < 4; ++m_) \
        _Pragma("unroll") \
        for (int n_ = 0; n_ < 4; ++n_) \
            acc[(q) * 4 + m_][n_] = __builtin_amdgcn_mfma_f32_16x16x32_bf16( \
                afx[m_], bqx[n_], acc[(q) * 4 + m_][n_], 0, 0, 0); \
    __builtin_amdgcn_s_setprio(0); }

    // Prologue: tiles 0 and 1 fully staged (8 loads in flight/wave).
    STAGE(0, 0, 0); STAGE(0, 0, 1); STAGE(0, 1, 0); STAGE(0, 1, 1);
    STAGE(1, 0, 0); STAGE(1, 0, 1); STAGE(1, 1, 0); STAGE(1, 1, 1);
    VMCNT(4);            // tile 0 complete; tile 1 still in flight
    BARRIER();
    RD_B(bq_a, 0); RD_A(af_a, 0, 0);

    // Main loop: tiles 0..29 in pairs, fully unrolled (static buffers/offsets).
    // Per tile: 12 ds_read_b128, 4 global_load_lds, 32 MFMA, 1 VMCNT, 1 barrier.
#pragma unroll
    for (int tp = 0; tp < 15; ++tp) {
        const int t = 2 * tp;
        // ---- tile t (even, consumes bq_a) ----
        RD_A(af_b, t, 1);
        STAGE(t + 2, 0, 0); STAGE(t + 2, 0, 1);
        MM(af_a, bq_a, 0);
        VMCNT(2);                 // drain tile t+1 staging (t+2 A stays in flight)
        BARRIER();
        RD_B(bq_b, t + 1); RD_A(af_a, t + 1, 0);
        STAGE(t + 2, 1, 0); STAGE(t + 2, 1, 1);
        MM(af_b, bq_a, 1);
        // ---- tile t+1 (odd, consumes bq_b) ----
        RD_A(af_b, t + 1, 1);
        STAGE(t + 3, 0, 0); STAGE(t + 3, 0, 1);
        MM(af_a, bq_b, 0);
        VMCNT(2);                 // drain tile t+2 staging
        BARRIER();
        RD_B(bq_a, t + 2); RD_A(af_a, t + 2, 0);
        STAGE(t + 3, 1, 0); STAGE(t + 3, 1, 1);
        MM(af_b, bq_b, 1);
    }

    // ---- tile 30 (even) ----
    RD_A(af_b, 30, 1);
    MM(af_a, bq_a, 0);
    VMCNT(0);                     // drain tile 31 staging (last outstanding)
    BARRIER();
    RD_B(bq_b, 31); RD_A(af_a, 31, 0);
    MM(af_b, bq_a, 1);
    // ---- tile 31 (odd) ----
    RD_A(af_b, 31, 1);
    MM(af_a, bq_b, 0);
    MM(af_b, bq_b, 1);

#undef MM
#undef RD_B
#undef RD_A
#undef STAGE

    // ---------------- epilogue: cos write + fused loss partials ------------
    __syncthreads();                 // full drain; LDS buffers now reusable
    float* pl = reinterpret_cast<float*>(lds);   // [256 rows][4 wc][2] floats

    float nbv[4]; int labc[4];
#pragma unroll
    for (int n = 0; n < 4; ++n) {
        int c = n0 + wc * 64 + n * 16 + l15;
        nbv[n] = nb[c]; labc[n] = labels[c];
    }

#pragma unroll
    for (int m = 0; m < 8; ++m) {
#pragma unroll
        for (int jj = 0; jj < 4; ++jj) {
            int rl = wr * 128 + m * 16 + lg * 4 + jj;   // 0..255
            int r  = m0 + rl;
            float nav = na[r]; int labr = labels[r];
            float es = 0.f, ms = 0.f;
#pragma unroll
            for (int n = 0; n < 4; ++n) {
                int c = n0 + wc * 64 + n * 16 + l15;
                float v = acc[m][n][jj] / fmaxf(nav * nbv[n], 1e-8f);
                C[(size_t)r * NB + c] = v;
                es += __expf(v);
                ms += (labc[n] == labr) ? v : 0.f;
            }
#pragma unroll
            for (int off = 1; off < 16; off <<= 1) {
                es += __shfl_xor(es, off);
                ms += __shfl_xor(ms, off);
            }
            if (l15 == 0) {
                int o = (rl * 4 + wc) * 2;
                pl[o] = es; pl[o + 1] = ms;
            }
        }
    }
    __syncthreads();
    if (tid < 256) {
        float es = 0.f, ms = 0.f;
#pragma unroll
        for (int w = 0; w < 4; ++w) {
            es += pl[(tid * 4 + w) * 2];
            ms += pl[(tid * 4 + w) * 2 + 1];
        }
        int grow = m0 + tid;
        pe[tn * NB + grow] = es;
        pm[tn * NB + grow] = ms;
    }
}

// ---------------------------------------------------------------------------
// Kernel 4: reduce column-tile partials -> per-row loss.
// ---------------------------------------------------------------------------
__global__ __launch_bounds__(256) void loss_final(
    const float* __restrict__ pe, const float* __restrict__ pm,
    const int* __restrict__ labels, const int* __restrict__ hist,
    float* __restrict__ per_row)
{
    int row = blockIdx.x * 256 + threadIdx.x;
    float es = 0.f, ms = 0.f;
#pragma unroll
    for (int t = 0; t < 32; ++t) {
        es += pe[t * NB + row];
        ms += pm[t * NB + row];
    }
    per_row[row] = logf(es) - ms / (float)hist[labels[row]];
}

// ---------------------------------------------------------------------------
// Kernel 5: deterministic mean of per_row -> out[0]
// ---------------------------------------------------------------------------
__global__ __launch_bounds__(256) void finalize(
    const float* __restrict__ per_row, float* __restrict__ out)
{
    __shared__ float sm[256];
    float s = 0.f;
    for (int i = threadIdx.x; i < NB; i += 256) s += per_row[i];
    sm[threadIdx.x] = s;
    __syncthreads();
    for (int k = 128; k; k >>= 1) {
        if (threadIdx.x < k) sm[threadIdx.x] += sm[threadIdx.x + k];
        __syncthreads();
    }
    if (threadIdx.x == 0) out[0] = sm[0] * (1.0f / (float)NB);
}

extern "C" void kernel_launch(void* const* d_in, const int* in_sizes, int n_in,
                              void* d_out, int out_size, void* d_ws, size_t ws_size,
                              hipStream_t stream) {
    const int*   labels = (const int*)d_in[0];
    const float* A      = (const float*)d_in[1];
    const float* Bm     = (const float*)d_in[2];
    float* out = (float*)d_out;

    // workspace layout (~36.2 MB)
    char* ws = (char*)d_ws;
    unsigned short* wa = (unsigned short*)(ws);                     // 16 MB
    unsigned short* wb = (unsigned short*)(ws + 16777216);          // 16 MB
    float* na      = (float*)(ws + 33554432);                       // 32 KB
    float* nb      = (float*)(ws + 33554432 + 32768);               // 32 KB
    float* per_row = (float*)(ws + 33554432 + 65536);               // 32 KB
    int*   hist    = (int*)  (ws + 33554432 + 98304);               // 512 B
    float* pe      = (float*)(ws + 33554432 + 131072);              // 1 MB
    float* pm      = (float*)(ws + 33554432 + 131072 + 1048576);    // 1 MB

    float* cosm = out + 1;   // out[0]=loss, out[1..] = cos_score row-major

    prep_kernel<<<4096, 256, 0, stream>>>(A, Bm, wa, wb, na, nb);
    hist_kernel<<<1,    256, 0, stream>>>(labels, hist);
    gemm_cos   <<<1024, 512, 0, stream>>>(wa, wb, na, nb, labels, cosm, pe, pm);
    loss_final <<<32,   256, 0, stream>>>(pe, pm, labels, hist, per_row);
    finalize   <<<1,    256, 0, stream>>>(per_row, out);
}